// Round 11
// baseline (197.336 us; speedup 1.0000x reference)
//
#include <hip/hip_runtime.h>
#include <hip/hip_bf16.h>

typedef __bf16 bf16_t;
typedef bf16_t bf16x8 __attribute__((ext_vector_type(8)));
typedef bf16_t bf16x4 __attribute__((ext_vector_type(4)));
typedef short  short4v __attribute__((ext_vector_type(4)));
typedef float  f32x4  __attribute__((ext_vector_type(4)));

#define MFMA16(a,b,c) __builtin_amdgcn_mfma_f32_16x16x32_bf16(a, b, c, 0, 0, 0)

constexpr int S = 2048, H = 16, Dh = 64;
constexpr int N = H * Dh;   // 1024
constexpr int K = 1024;     // E
constexpr float QSCALE = 0.125f * 1.4426950408889634f;  // 1/sqrt(64) * log2(e)

static __device__ inline void load_lds16(const bf16_t* g, bf16_t* l) {
  __builtin_amdgcn_global_load_lds(
      (const __attribute__((address_space(1))) void*)g,
      (__attribute__((address_space(3))) void*)l, 16, 0, 0);
}

static __device__ inline ushort f2bb(float x) {
  bf16_t h = (bf16_t)x;
  return __builtin_bit_cast(ushort, h);
}

// ---------------------------------------------------------------------------
// prep (R5-verified): blocks 0..6143 convert X fp32->bf16; blocks 6144..6911
// transpose W.
// ---------------------------------------------------------------------------
__global__ __launch_bounds__(256) void prep(
    const float* __restrict__ q, const float* __restrict__ k,
    const float* __restrict__ v,
    const float* __restrict__ wq, const float* __restrict__ wk,
    const float* __restrict__ wv,
    bf16_t* __restrict__ xq, bf16_t* __restrict__ xk, bf16_t* __restrict__ xv,
    bf16_t* __restrict__ wtq, bf16_t* __restrict__ wtk, bf16_t* __restrict__ wtv) {
  __shared__ ushort tile[64][68];
  int bx = blockIdx.x, t = threadIdx.x;
  if (bx < 6144) {
    int z = bx >> 11, bb = bx & 2047;
    const float* xi = z == 0 ? q : z == 1 ? k : v;
    bf16_t*      xo = z == 0 ? xq : z == 1 ? xk : xv;
    size_t idx = ((size_t)bb * 256 + t) * 8;
    float4 a = *(const float4*)&xi[idx];
    float4 b = *(const float4*)&xi[idx + 4];
    bf16x8 w;
    w[0] = (bf16_t)a.x; w[1] = (bf16_t)a.y; w[2] = (bf16_t)a.z; w[3] = (bf16_t)a.w;
    w[4] = (bf16_t)b.x; w[5] = (bf16_t)b.y; w[6] = (bf16_t)b.z; w[7] = (bf16_t)b.w;
    *(bf16x8*)&xo[idx] = w;
  } else {
    int zz = bx - 6144;
    int z = zz >> 8, bb = zz & 255;
    const float* wi = z == 0 ? wq : z == 1 ? wk : wv;
    ushort*      wo = (ushort*)(z == 0 ? wtq : z == 1 ? wtk : wtv);
    int k0 = (bb >> 4) * 64, n0 = (bb & 15) * 64;
    for (int i = 0; i < 4; ++i) {
      int idx4 = (i * 256 + t) * 4;
      int r = idx4 >> 6, c = idx4 & 63;
      float4 vv = *(const float4*)&wi[(size_t)(k0 + r) * N + n0 + c];
      tile[r][c] = f2bb(vv.x); tile[r][c + 1] = f2bb(vv.y);
      tile[r][c + 2] = f2bb(vv.z); tile[r][c + 3] = f2bb(vv.w);
    }
    __syncthreads();
    for (int i = 0; i < 4; ++i) {
      int idx4 = (i * 256 + t) * 4;
      int r = idx4 >> 6, c = idx4 & 63;
      ushort4 vv;
      vv.x = tile[c][r]; vv.y = tile[c + 1][r];
      vv.z = tile[c + 2][r]; vv.w = tile[c + 3][r];
      *(ushort4*)&wo[(size_t)(n0 + r) * K + k0 + c] = vv;
    }
  }
}

// ---------------------------------------------------------------------------
// Projection GEMM (R5-verified: m97 2-barrier DMA staging both operands,
// XOR swizzle, XCD-chunked flat-768 mapping, LDS-staged coalesced epilogue).
// ---------------------------------------------------------------------------
__global__ __launch_bounds__(256) void proj_gemm(
    const bf16_t* __restrict__ xq, const bf16_t* __restrict__ xk,
    const bf16_t* __restrict__ xv,
    const bf16_t* __restrict__ wtq, const bf16_t* __restrict__ wtk,
    const bf16_t* __restrict__ wtv,
    const float* __restrict__ bq, const float* __restrict__ bk,
    const float* __restrict__ bv,
    bf16_t* __restrict__ qh, bf16_t* __restrict__ kh, bf16_t* __restrict__ vt) {
  int bid = blockIdx.x;                       // 0..767
  int logical = (bid & 7) * 96 + (bid >> 3);  // XCD-chunked, bijective
  int mode = logical >> 8;                    // 256 logicals per mode
  int rem = logical & 255;
  int gx = rem & 7;                           // N-tile (fastest within XCD)
  int gy = rem >> 3;                          // M-tile

  const bf16_t* X  = mode == 0 ? xq  : mode == 1 ? xk  : wtv;  // A rows
  const bf16_t* Wt = mode == 0 ? wtq : mode == 1 ? wtk : xv;   // B rows
  const float*  Bi = mode == 0 ? bq  : mode == 1 ? bk  : bv;

  __shared__ __align__(16) bf16_t smem[17408];   // 34.8 KB
  bf16_t (*Ash)[64] = (bf16_t(*)[64])smem;
  bf16_t (*Bsh)[64] = (bf16_t(*)[64])(smem + 8192);
  bf16_t* Cs = smem;

  int tid = threadIdx.x;
  int wave = tid >> 6, lane = tid & 63;
  int lr = lane & 15, lg = lane >> 4;
  int lrow = lane >> 3, lchunk = lane & 7;
  int m0 = (mode < 2 ? gy : gx) * 128;
  int n0 = (mode < 2 ? gx : gy) * 128;
  int wm = (wave >> 1) * 64, wn = (wave & 1) * 64;

  f32x4 acc[4][4];
  for (int i = 0; i < 4; ++i)
    for (int j = 0; j < 4; ++j) acc[i][j] = (f32x4){0.f, 0.f, 0.f, 0.f};

  for (int ko = 0; ko < K / 64; ++ko) {
    __syncthreads();
    for (int j = 0; j < 4; ++j) {
      int r = wave * 32 + j * 8 + lrow;
      int gc = (lchunk ^ (r & 7)) * 8;
      load_lds16(&X [(size_t)(m0 + r) * K + ko * 64 + gc], &Ash[r][lchunk * 8]);
      load_lds16(&Wt[(size_t)(n0 + r) * K + ko * 64 + gc], &Bsh[r][lchunk * 8]);
    }
    __syncthreads();
    for (int kk = 0; kk < 2; ++kk) {
      bf16x8 af[4], bfr[4];
      for (int i = 0; i < 4; ++i) {
        int rr = wm + i * 16 + lr;
        af[i] = *(const bf16x8*)&Ash[rr][(((kk << 2) | lg) ^ (rr & 7)) * 8];
      }
      for (int j = 0; j < 4; ++j) {
        int rr = wn + j * 16 + lr;
        bfr[j] = *(const bf16x8*)&Bsh[rr][(((kk << 2) | lg) ^ (rr & 7)) * 8];
      }
      for (int i = 0; i < 4; ++i)
        for (int j = 0; j < 4; ++j)
          acc[i][j] = MFMA16(af[i], bfr[j], acc[i][j]);
    }
  }

  float badd[4][4][4];
  if (mode < 2) {
    float bvv[4];
    for (int j = 0; j < 4; ++j) bvv[j] = Bi[n0 + wn + j * 16 + lr];
    for (int i = 0; i < 4; ++i)
      for (int j = 0; j < 4; ++j)
        for (int r = 0; r < 4; ++r) badd[i][j][r] = bvv[j];
  } else {
    for (int i = 0; i < 4; ++i)
      for (int r = 0; r < 4; ++r) {
        float bm = Bi[m0 + wm + i * 16 + lg * 4 + r];
        for (int j = 0; j < 4; ++j) badd[i][j][r] = bm;
      }
  }

  __syncthreads();
  for (int i = 0; i < 4; ++i)
    for (int j = 0; j < 4; ++j)
      for (int r = 0; r < 4; ++r) {
        float vvv = acc[i][j][r] + badd[i][j][r];
        if (mode == 0) vvv *= QSCALE;
        Cs[(size_t)(wm + i * 16 + lg * 4 + r) * 136 + wn + j * 16 + lr] = (bf16_t)vvv;
      }
  __syncthreads();

  bf16_t* o = mode == 0 ? qh : mode == 1 ? kh : vt;
  for (int p = 0; p < 8; ++p) {
    int idx = p * 256 + tid;
    int row = idx >> 4, ch = idx & 15;
    bf16x8 vv = *(const bf16x8*)&Cs[(size_t)row * 136 + ch * 8];
    size_t dst;
    if (mode < 2) {
      int m_g = m0 + row, n_g = n0 + ch * 8;
      int b = m_g >> 11, s = m_g & 2047;
      int h = n_g >> 6, d = n_g & 63;
      dst = (((size_t)(b * 16 + h) * 2048) + s) * 64 + d;
    } else {
      int w_g = m0 + row, t_g = n0 + ch * 8;
      int b = t_g >> 11, s = t_g & 2047;
      dst = ((size_t)(b * 1024 + w_g)) * 2048 + s;
    }
    *(uint4*)&o[dst] = __builtin_bit_cast(uint4, vv);
  }
}

// ---------------------------------------------------------------------------
// Flash attention v12 = v11 (R10-verified, 50.8-52.4 us: v7 structure +
// XCD-chunked mapping) + s_setprio(1) around the compute phase (QK^T + exp2
// + PV).  Mechanism [learn_hip m191, attn +4-7%]: with 2 independent blocks
// per CU, waves of one block in their compute chain get issue priority over
// the other block's staging/address-calc waves -- fills the ~55% uncovered
// stall measured in R10 (max single pipe 45%: LDS; MFMA 28%, VALU 32%).
// Staging + prefetch stay at priority 0.  No math change.
// ---------------------------------------------------------------------------
__global__ __launch_bounds__(512, 2) void attn(
    const bf16_t* __restrict__ qh, const bf16_t* __restrict__ kh,
    const bf16_t* __restrict__ vt, float* __restrict__ out) {
  // staging: [half][kt 8KB | vs 8KB] = 32 KB; merge overlay needs 33280 B
  __shared__ __align__(16) bf16_t smem[16640];

  int tid = threadIdx.x, wave = tid >> 6, lane = tid & 63;
  int lr = lane & 15, lg = lane >> 4;
  int half = wave >> 2, w4 = wave & 3;

  int bid = blockIdx.x;
  int logical = (bid & 7) * 64 + (bid >> 3);  // XCD-chunked, bijective (512%8==0)
  int bh = logical >> 4;
  int q0 = (logical & 15) * 128 + w4 * 32;

  bf16_t* kt = smem + half * 8192;
  bf16_t* vs = kt + 4096;

  const bf16_t* qg = qh + (size_t)bh * S * Dh;
  const bf16_t* kg = kh + (size_t)bh * S * Dh;
  const bf16_t* vg = vt + (size_t)bh * Dh * S;

  bf16x8 bqf[2][2];
#pragma unroll
  for (int ms = 0; ms < 2; ++ms)
#pragma unroll
    for (int kk = 0; kk < 2; ++kk)
      bqf[ms][kk] = *(const bf16x8*)
          &qg[(size_t)(q0 + ms * 16 + lr) * 64 + kk * 32 + lg * 8];

  bf16x8 ones8;
#pragma unroll
  for (int j = 0; j < 8; ++j) ones8[j] = (bf16_t)1.0f;

  f32x4 o_acc[2][4], lacc[2];
#pragma unroll
  for (int ms = 0; ms < 2; ++ms) {
    lacc[ms] = (f32x4){0.f, 0.f, 0.f, 0.f};
#pragma unroll
    for (int dt = 0; dt < 4; ++dt) o_acc[ms][dt] = (f32x4){0.f, 0.f, 0.f, 0.f};
  }

  // staging geometry within the half (256 threads cover 64 rows x 8 chunks,
  // two 16B slots per thread per matrix)
  int lrow = lane >> 3, lchunk = lane & 7;
  int srow0 = w4 * 16 + lrow;
  int srow1 = srow0 + 8;
  int sgc = (lchunk ^ (srow0 & 7)) * 8;   // (srow1&7)==(srow0&7)
  int ld0 = srow0 * 64 + lchunk * 8;
  int ld1 = ld0 + 512;                    // +8 rows

  int cb = half * (S / 2);                // this half's kv col base

  // prologue: prefetch this half's tile 0 into VGPRs
  uint4 kr0 = *(const uint4*)&kg[(size_t)(cb + srow0) * 64 + sgc];
  uint4 kr1 = *(const uint4*)&kg[(size_t)(cb + srow1) * 64 + sgc];
  uint4 vr0 = *(const uint4*)&vg[(size_t)srow0 * S + cb + sgc];
  uint4 vr1 = *(const uint4*)&vg[(size_t)srow1 * S + cb + sgc];

  int sw = lr & 7, p4 = (lg & 1) * 4;

  constexpr int NITH = (S / 2) / 64;      // 16
  for (int it = 0; it < NITH; ++it) {
    __syncthreads();                      // prev iter's LDS reads retired
    *(uint4*)&kt[ld0] = kr0;              // waits vmcnt for OWN loads only
    *(uint4*)&kt[ld1] = kr1;
    *(uint4*)&vs[ld0] = vr0;
    *(uint4*)&vs[ld1] = vr1;
    if (it + 1 < NITH) {                  // prefetch tile i+1; lands in compute
      int sk1 = cb + (it + 1) * 64;
      kr0 = *(const uint4*)&kg[(size_t)(sk1 + srow0) * 64 + sgc];
      kr1 = *(const uint4*)&kg[(size_t)(sk1 + srow1) * 64 + sgc];
      vr0 = *(const uint4*)&vg[(size_t)srow0 * S + sk1 + sgc];
      vr1 = *(const uint4*)&vg[(size_t)srow1 * S + sk1 + sgc];
    }
    __syncthreads();                      // ds_writes visible to half's waves

    __builtin_amdgcn_s_setprio(1);        // compute phase: elevated priority

    // QK^T (swapped operands: A=K, B=Q -> lane holds scores for q-row lr),
    // processed in two tp groups of 32 k-cols; st/ak transient per group.
    // pa8[ms][tp] slot j holds P[q=lr][k = tp*32 + (j>>2)*16 + lg*4 + (j&3)]
    bf16x8 pa8[2][2];
#pragma unroll
    for (int tp = 0; tp < 2; ++tp) {
      f32x4 st[2][2];
#pragma unroll
      for (int ms = 0; ms < 2; ++ms)
#pragma unroll
        for (int ts = 0; ts < 2; ++ts) st[ms][ts] = (f32x4){0.f, 0.f, 0.f, 0.f};
#pragma unroll
      for (int ts = 0; ts < 2; ++ts) {
        int t = tp * 2 + ts;
        const bf16_t* krow = &kt[(t * 16 + lr) * 64];
        bf16x8 ak0 = *(const bf16x8*)&krow[(lg ^ sw) * 8];
        bf16x8 ak1 = *(const bf16x8*)&krow[((4 + lg) ^ sw) * 8];
#pragma unroll
        for (int ms = 0; ms < 2; ++ms) {
          st[ms][ts] = MFMA16(ak0, bqf[ms][0], st[ms][ts]);
          st[ms][ts] = MFMA16(ak1, bqf[ms][1], st[ms][ts]);
        }
      }
#pragma unroll
      for (int ms = 0; ms < 2; ++ms)
#pragma unroll
        for (int r = 0; r < 4; ++r) {
          pa8[ms][tp][r]     = (bf16_t)__builtin_amdgcn_exp2f(st[ms][0][r]);
          pa8[ms][tp][r + 4] = (bf16_t)__builtin_amdgcn_exp2f(st[ms][1][r]);
        }
    }

    // PV at full k=32 rate; V fragments built transiently per dt, shared by
    // both Q-tiles.
#pragma unroll
    for (int tp = 0; tp < 2; ++tp) {
      int g0 = tp * 4 + (lg >> 1);
#pragma unroll
      for (int dt = 0; dt < 4; ++dt) {
        const bf16_t* vrow = &vs[(dt * 16 + lr) * 64];
        bf16x4 lo = *(const bf16x4*)&vrow[((g0      ^ sw) * 8) + p4];
        bf16x4 hi = *(const bf16x4*)&vrow[(((g0 + 2) ^ sw) * 8) + p4];
        bf16x8 bb;
#pragma unroll
        for (int j = 0; j < 4; ++j) { bb[j] = lo[j]; bb[j + 4] = hi[j]; }
#pragma unroll
        for (int ms = 0; ms < 2; ++ms)
          o_acc[ms][dt] = MFMA16(pa8[ms][tp], bb, o_acc[ms][dt]);
      }
#pragma unroll
      for (int ms = 0; ms < 2; ++ms)
        lacc[ms] = MFMA16(pa8[ms][tp], ones8, lacc[ms]);
    }

    __builtin_amdgcn_s_setprio(0);        // back to base for staging/barrier
  }

  // ---- merge halves via LDS overlay (reuses staging space) ----
  __syncthreads();                        // all staging reads/writes retired
  float* mo = (float*)smem;               // [8 q-subtiles][16 rows][64 cols]
  float* ls = mo + 8 * 16 * 64;           // [8][16] rowsums

  if (half == 1) {
#pragma unroll
    for (int ms = 0; ms < 2; ++ms)
#pragma unroll
      for (int r = 0; r < 4; ++r) {
        int row = (w4 * 2 + ms) * 16 + lg * 4 + r;
#pragma unroll
        for (int dt = 0; dt < 4; ++dt)
          mo[row * 64 + dt * 16 + lr] = o_acc[ms][dt][r];
        if (lr == 0) ls[row] = lacc[ms][r];
      }
  }
  __syncthreads();
  if (half == 0) {
    int b = bh >> 4, hh = bh & 15;
#pragma unroll
    for (int ms = 0; ms < 2; ++ms)
#pragma unroll
      for (int r = 0; r < 4; ++r) {
        int row = (w4 * 2 + ms) * 16 + lg * 4 + r;
        float inv = 1.f / (lacc[ms][r] + ls[row]);
        int s_row = q0 + ms * 16 + lg * 4 + r;
        size_t base = ((size_t)(b * S + s_row)) * 1024 + hh * 64;
#pragma unroll
        for (int dt = 0; dt < 4; ++dt)
          out[base + dt * 16 + lr] =
              (o_acc[ms][dt][r] + mo[row * 64 + dt * 16 + lr]) * inv;
      }
  }
}

// ---------------------------------------------------------------------------
extern "C" void kernel_launch(void* const* d_in, const int* in_sizes, int n_in,
                              void* d_out, int out_size, void* d_ws, size_t ws_size,
                              hipStream_t stream) {
  const float* q  = (const float*)d_in[0];
  const float* k  = (const float*)d_in[1];
  const float* v  = (const float*)d_in[2];
  const float* wq = (const float*)d_in[3];
  const float* bq = (const float*)d_in[4];
  const float* wk = (const float*)d_in[5];
  const float* bk = (const float*)d_in[6];
  const float* wv = (const float*)d_in[7];
  const float* bv = (const float*)d_in[8];

  bf16_t* ws  = (bf16_t*)d_ws;
  constexpr size_t MW = (size_t)1 << 20;
  constexpr size_t MX = (size_t)4096 * 1024;
  bf16_t* wtq = ws;
  bf16_t* wtk = wtq + MW;
  bf16_t* wtv = wtk + MW;
  bf16_t* xq  = wtv + MW;
  bf16_t* xk  = xq + MX;
  bf16_t* xv  = xk + MX;
  bf16_t* qhd = xv + MX;
  bf16_t* khd = qhd + MX;
  bf16_t* vtd = khd + MX;
  float* out  = (float*)d_out;

  prep<<<6912, 256, 0, stream>>>(q, k, v, wq, wk, wv,
                                 xq, xk, xv, wtq, wtk, wtv);
  proj_gemm<<<768, 256, 0, stream>>>(xq, xk, xv, wtq, wtk, wtv,
                                     bq, bk, bv, qhd, khd, vtd);
  attn<<<512, 512, 0, stream>>>(qhd, khd, vtd, out);
}

// Round 12
// 196.338 us; speedup vs baseline: 1.0051x; 1.0051x over previous
//
#include <hip/hip_runtime.h>
#include <hip/hip_bf16.h>

typedef __bf16 bf16_t;
typedef bf16_t bf16x8 __attribute__((ext_vector_type(8)));
typedef bf16_t bf16x4 __attribute__((ext_vector_type(4)));
typedef short  short4v __attribute__((ext_vector_type(4)));
typedef float  f32x4  __attribute__((ext_vector_type(4)));

#define MFMA16(a,b,c) __builtin_amdgcn_mfma_f32_16x16x32_bf16(a, b, c, 0, 0, 0)

constexpr int S = 2048, H = 16, Dh = 64;
constexpr int N = H * Dh;   // 1024
constexpr int K = 1024;     // E
constexpr float QSCALE = 0.125f * 1.4426950408889634f;  // 1/sqrt(64) * log2(e)

static __device__ inline void load_lds16(const bf16_t* g, bf16_t* l) {
  __builtin_amdgcn_global_load_lds(
      (const __attribute__((address_space(1))) void*)g,
      (__attribute__((address_space(3))) void*)l, 16, 0, 0);
}

static __device__ inline ushort f2bb(float x) {
  bf16_t h = (bf16_t)x;
  return __builtin_bit_cast(ushort, h);
}

// ---------------------------------------------------------------------------
// prep (R5-verified): blocks 0..6143 convert X fp32->bf16; blocks 6144..6911
// transpose W.
// ---------------------------------------------------------------------------
__global__ __launch_bounds__(256) void prep(
    const float* __restrict__ q, const float* __restrict__ k,
    const float* __restrict__ v,
    const float* __restrict__ wq, const float* __restrict__ wk,
    const float* __restrict__ wv,
    bf16_t* __restrict__ xq, bf16_t* __restrict__ xk, bf16_t* __restrict__ xv,
    bf16_t* __restrict__ wtq, bf16_t* __restrict__ wtk, bf16_t* __restrict__ wtv) {
  __shared__ ushort tile[64][68];
  int bx = blockIdx.x, t = threadIdx.x;
  if (bx < 6144) {
    int z = bx >> 11, bb = bx & 2047;
    const float* xi = z == 0 ? q : z == 1 ? k : v;
    bf16_t*      xo = z == 0 ? xq : z == 1 ? xk : xv;
    size_t idx = ((size_t)bb * 256 + t) * 8;
    float4 a = *(const float4*)&xi[idx];
    float4 b = *(const float4*)&xi[idx + 4];
    bf16x8 w;
    w[0] = (bf16_t)a.x; w[1] = (bf16_t)a.y; w[2] = (bf16_t)a.z; w[3] = (bf16_t)a.w;
    w[4] = (bf16_t)b.x; w[5] = (bf16_t)b.y; w[6] = (bf16_t)b.z; w[7] = (bf16_t)b.w;
    *(bf16x8*)&xo[idx] = w;
  } else {
    int zz = bx - 6144;
    int z = zz >> 8, bb = zz & 255;
    const float* wi = z == 0 ? wq : z == 1 ? wk : wv;
    ushort*      wo = (ushort*)(z == 0 ? wtq : z == 1 ? wtk : wtv);
    int k0 = (bb >> 4) * 64, n0 = (bb & 15) * 64;
    for (int i = 0; i < 4; ++i) {
      int idx4 = (i * 256 + t) * 4;
      int r = idx4 >> 6, c = idx4 & 63;
      float4 vv = *(const float4*)&wi[(size_t)(k0 + r) * N + n0 + c];
      tile[r][c] = f2bb(vv.x); tile[r][c + 1] = f2bb(vv.y);
      tile[r][c + 2] = f2bb(vv.z); tile[r][c + 3] = f2bb(vv.w);
    }
    __syncthreads();
    for (int i = 0; i < 4; ++i) {
      int idx4 = (i * 256 + t) * 4;
      int r = idx4 >> 6, c = idx4 & 63;
      ushort4 vv;
      vv.x = tile[c][r]; vv.y = tile[c + 1][r];
      vv.z = tile[c + 2][r]; vv.w = tile[c + 3][r];
      *(ushort4*)&wo[(size_t)(n0 + r) * K + k0 + c] = vv;
    }
  }
}

// ---------------------------------------------------------------------------
// Projection GEMM (R5-verified: m97 2-barrier DMA staging both operands,
// XOR swizzle, XCD-chunked flat-768 mapping, LDS-staged coalesced epilogue).
// ---------------------------------------------------------------------------
__global__ __launch_bounds__(256) void proj_gemm(
    const bf16_t* __restrict__ xq, const bf16_t* __restrict__ xk,
    const bf16_t* __restrict__ xv,
    const bf16_t* __restrict__ wtq, const bf16_t* __restrict__ wtk,
    const bf16_t* __restrict__ wtv,
    const float* __restrict__ bq, const float* __restrict__ bk,
    const float* __restrict__ bv,
    bf16_t* __restrict__ qh, bf16_t* __restrict__ kh, bf16_t* __restrict__ vt) {
  int bid = blockIdx.x;                       // 0..767
  int logical = (bid & 7) * 96 + (bid >> 3);  // XCD-chunked, bijective
  int mode = logical >> 8;                    // 256 logicals per mode
  int rem = logical & 255;
  int gx = rem & 7;                           // N-tile (fastest within XCD)
  int gy = rem >> 3;                          // M-tile

  const bf16_t* X  = mode == 0 ? xq  : mode == 1 ? xk  : wtv;  // A rows
  const bf16_t* Wt = mode == 0 ? wtq : mode == 1 ? wtk : xv;   // B rows
  const float*  Bi = mode == 0 ? bq  : mode == 1 ? bk  : bv;

  __shared__ __align__(16) bf16_t smem[17408];   // 34.8 KB
  bf16_t (*Ash)[64] = (bf16_t(*)[64])smem;
  bf16_t (*Bsh)[64] = (bf16_t(*)[64])(smem + 8192);
  bf16_t* Cs = smem;

  int tid = threadIdx.x;
  int wave = tid >> 6, lane = tid & 63;
  int lr = lane & 15, lg = lane >> 4;
  int lrow = lane >> 3, lchunk = lane & 7;
  int m0 = (mode < 2 ? gy : gx) * 128;
  int n0 = (mode < 2 ? gx : gy) * 128;
  int wm = (wave >> 1) * 64, wn = (wave & 1) * 64;

  f32x4 acc[4][4];
  for (int i = 0; i < 4; ++i)
    for (int j = 0; j < 4; ++j) acc[i][j] = (f32x4){0.f, 0.f, 0.f, 0.f};

  for (int ko = 0; ko < K / 64; ++ko) {
    __syncthreads();
    for (int j = 0; j < 4; ++j) {
      int r = wave * 32 + j * 8 + lrow;
      int gc = (lchunk ^ (r & 7)) * 8;
      load_lds16(&X [(size_t)(m0 + r) * K + ko * 64 + gc], &Ash[r][lchunk * 8]);
      load_lds16(&Wt[(size_t)(n0 + r) * K + ko * 64 + gc], &Bsh[r][lchunk * 8]);
    }
    __syncthreads();
    for (int kk = 0; kk < 2; ++kk) {
      bf16x8 af[4], bfr[4];
      for (int i = 0; i < 4; ++i) {
        int rr = wm + i * 16 + lr;
        af[i] = *(const bf16x8*)&Ash[rr][(((kk << 2) | lg) ^ (rr & 7)) * 8];
      }
      for (int j = 0; j < 4; ++j) {
        int rr = wn + j * 16 + lr;
        bfr[j] = *(const bf16x8*)&Bsh[rr][(((kk << 2) | lg) ^ (rr & 7)) * 8];
      }
      for (int i = 0; i < 4; ++i)
        for (int j = 0; j < 4; ++j)
          acc[i][j] = MFMA16(af[i], bfr[j], acc[i][j]);
    }
  }

  float badd[4][4][4];
  if (mode < 2) {
    float bvv[4];
    for (int j = 0; j < 4; ++j) bvv[j] = Bi[n0 + wn + j * 16 + lr];
    for (int i = 0; i < 4; ++i)
      for (int j = 0; j < 4; ++j)
        for (int r = 0; r < 4; ++r) badd[i][j][r] = bvv[j];
  } else {
    for (int i = 0; i < 4; ++i)
      for (int r = 0; r < 4; ++r) {
        float bm = Bi[m0 + wm + i * 16 + lg * 4 + r];
        for (int j = 0; j < 4; ++j) badd[i][j][r] = bm;
      }
  }

  __syncthreads();
  for (int i = 0; i < 4; ++i)
    for (int j = 0; j < 4; ++j)
      for (int r = 0; r < 4; ++r) {
        float vvv = acc[i][j][r] + badd[i][j][r];
        if (mode == 0) vvv *= QSCALE;
        Cs[(size_t)(wm + i * 16 + lg * 4 + r) * 136 + wn + j * 16 + lr] = (bf16_t)vvv;
      }
  __syncthreads();

  bf16_t* o = mode == 0 ? qh : mode == 1 ? kh : vt;
  for (int p = 0; p < 8; ++p) {
    int idx = p * 256 + tid;
    int row = idx >> 4, ch = idx & 15;
    bf16x8 vv = *(const bf16x8*)&Cs[(size_t)row * 136 + ch * 8];
    size_t dst;
    if (mode < 2) {
      int m_g = m0 + row, n_g = n0 + ch * 8;
      int b = m_g >> 11, s = m_g & 2047;
      int h = n_g >> 6, d = n_g & 63;
      dst = (((size_t)(b * 16 + h) * 2048) + s) * 64 + d;
    } else {
      int w_g = m0 + row, t_g = n0 + ch * 8;
      int b = t_g >> 11, s = t_g & 2047;
      dst = ((size_t)(b * 1024 + w_g)) * 2048 + s;
    }
    *(uint4*)&o[dst] = __builtin_bit_cast(uint4, vv);
  }
}

// ---------------------------------------------------------------------------
// Flash attention v11 (R10-verified session best, 50.8-52.4 us): v7 loop
// structure (single 33 KB buffer, 2 barriers/iter, KV-split halves, paired
// K=32 PV, register-prefetch staging) + XCD-chunked flat block mapping.
// R11's s_setprio graft REVERTED: it cost ~2 us (VGPR 72->80 regalloc
// perturbation; 8-wave barrier-locked blocks lack the phase diversity the
// technique needs -- m190-style null, not m191-style win).
// ---------------------------------------------------------------------------
__global__ __launch_bounds__(512, 2) void attn(
    const bf16_t* __restrict__ qh, const bf16_t* __restrict__ kh,
    const bf16_t* __restrict__ vt, float* __restrict__ out) {
  // staging: [half][kt 8KB | vs 8KB] = 32 KB; merge overlay needs 33280 B
  __shared__ __align__(16) bf16_t smem[16640];

  int tid = threadIdx.x, wave = tid >> 6, lane = tid & 63;
  int lr = lane & 15, lg = lane >> 4;
  int half = wave >> 2, w4 = wave & 3;

  int bid = blockIdx.x;
  int logical = (bid & 7) * 64 + (bid >> 3);  // XCD-chunked, bijective (512%8==0)
  int bh = logical >> 4;
  int q0 = (logical & 15) * 128 + w4 * 32;

  bf16_t* kt = smem + half * 8192;
  bf16_t* vs = kt + 4096;

  const bf16_t* qg = qh + (size_t)bh * S * Dh;
  const bf16_t* kg = kh + (size_t)bh * S * Dh;
  const bf16_t* vg = vt + (size_t)bh * Dh * S;

  bf16x8 bqf[2][2];
#pragma unroll
  for (int ms = 0; ms < 2; ++ms)
#pragma unroll
    for (int kk = 0; kk < 2; ++kk)
      bqf[ms][kk] = *(const bf16x8*)
          &qg[(size_t)(q0 + ms * 16 + lr) * 64 + kk * 32 + lg * 8];

  bf16x8 ones8;
#pragma unroll
  for (int j = 0; j < 8; ++j) ones8[j] = (bf16_t)1.0f;

  f32x4 o_acc[2][4], lacc[2];
#pragma unroll
  for (int ms = 0; ms < 2; ++ms) {
    lacc[ms] = (f32x4){0.f, 0.f, 0.f, 0.f};
#pragma unroll
    for (int dt = 0; dt < 4; ++dt) o_acc[ms][dt] = (f32x4){0.f, 0.f, 0.f, 0.f};
  }

  // staging geometry within the half (256 threads cover 64 rows x 8 chunks,
  // two 16B slots per thread per matrix)
  int lrow = lane >> 3, lchunk = lane & 7;
  int srow0 = w4 * 16 + lrow;
  int srow1 = srow0 + 8;
  int sgc = (lchunk ^ (srow0 & 7)) * 8;   // (srow1&7)==(srow0&7)
  int ld0 = srow0 * 64 + lchunk * 8;
  int ld1 = ld0 + 512;                    // +8 rows

  int cb = half * (S / 2);                // this half's kv col base

  // prologue: prefetch this half's tile 0 into VGPRs
  uint4 kr0 = *(const uint4*)&kg[(size_t)(cb + srow0) * 64 + sgc];
  uint4 kr1 = *(const uint4*)&kg[(size_t)(cb + srow1) * 64 + sgc];
  uint4 vr0 = *(const uint4*)&vg[(size_t)srow0 * S + cb + sgc];
  uint4 vr1 = *(const uint4*)&vg[(size_t)srow1 * S + cb + sgc];

  int sw = lr & 7, p4 = (lg & 1) * 4;

  constexpr int NITH = (S / 2) / 64;      // 16
  for (int it = 0; it < NITH; ++it) {
    __syncthreads();                      // prev iter's LDS reads retired
    *(uint4*)&kt[ld0] = kr0;              // waits vmcnt for OWN loads only
    *(uint4*)&kt[ld1] = kr1;
    *(uint4*)&vs[ld0] = vr0;
    *(uint4*)&vs[ld1] = vr1;
    if (it + 1 < NITH) {                  // prefetch tile i+1; lands in compute
      int sk1 = cb + (it + 1) * 64;
      kr0 = *(const uint4*)&kg[(size_t)(sk1 + srow0) * 64 + sgc];
      kr1 = *(const uint4*)&kg[(size_t)(sk1 + srow1) * 64 + sgc];
      vr0 = *(const uint4*)&vg[(size_t)srow0 * S + sk1 + sgc];
      vr1 = *(const uint4*)&vg[(size_t)srow1 * S + sk1 + sgc];
    }
    __syncthreads();                      // ds_writes visible to half's waves

    // QK^T (swapped operands: A=K, B=Q -> lane holds scores for q-row lr),
    // processed in two tp groups of 32 k-cols; st/ak transient per group.
    // pa8[ms][tp] slot j holds P[q=lr][k = tp*32 + (j>>2)*16 + lg*4 + (j&3)]
    bf16x8 pa8[2][2];
#pragma unroll
    for (int tp = 0; tp < 2; ++tp) {
      f32x4 st[2][2];
#pragma unroll
      for (int ms = 0; ms < 2; ++ms)
#pragma unroll
        for (int ts = 0; ts < 2; ++ts) st[ms][ts] = (f32x4){0.f, 0.f, 0.f, 0.f};
#pragma unroll
      for (int ts = 0; ts < 2; ++ts) {
        int t = tp * 2 + ts;
        const bf16_t* krow = &kt[(t * 16 + lr) * 64];
        bf16x8 ak0 = *(const bf16x8*)&krow[(lg ^ sw) * 8];
        bf16x8 ak1 = *(const bf16x8*)&krow[((4 + lg) ^ sw) * 8];
#pragma unroll
        for (int ms = 0; ms < 2; ++ms) {
          st[ms][ts] = MFMA16(ak0, bqf[ms][0], st[ms][ts]);
          st[ms][ts] = MFMA16(ak1, bqf[ms][1], st[ms][ts]);
        }
      }
#pragma unroll
      for (int ms = 0; ms < 2; ++ms)
#pragma unroll
        for (int r = 0; r < 4; ++r) {
          pa8[ms][tp][r]     = (bf16_t)__builtin_amdgcn_exp2f(st[ms][0][r]);
          pa8[ms][tp][r + 4] = (bf16_t)__builtin_amdgcn_exp2f(st[ms][1][r]);
        }
    }

    // PV at full k=32 rate; V fragments built transiently per dt, shared by
    // both Q-tiles.
#pragma unroll
    for (int tp = 0; tp < 2; ++tp) {
      int g0 = tp * 4 + (lg >> 1);
#pragma unroll
      for (int dt = 0; dt < 4; ++dt) {
        const bf16_t* vrow = &vs[(dt * 16 + lr) * 64];
        bf16x4 lo = *(const bf16x4*)&vrow[((g0      ^ sw) * 8) + p4];
        bf16x4 hi = *(const bf16x4*)&vrow[(((g0 + 2) ^ sw) * 8) + p4];
        bf16x8 bb;
#pragma unroll
        for (int j = 0; j < 4; ++j) { bb[j] = lo[j]; bb[j + 4] = hi[j]; }
#pragma unroll
        for (int ms = 0; ms < 2; ++ms)
          o_acc[ms][dt] = MFMA16(pa8[ms][tp], bb, o_acc[ms][dt]);
      }
#pragma unroll
      for (int ms = 0; ms < 2; ++ms)
        lacc[ms] = MFMA16(pa8[ms][tp], ones8, lacc[ms]);
    }
  }

  // ---- merge halves via LDS overlay (reuses staging space) ----
  __syncthreads();                        // all staging reads/writes retired
  float* mo = (float*)smem;               // [8 q-subtiles][16 rows][64 cols]
  float* ls = mo + 8 * 16 * 64;           // [8][16] rowsums

  if (half == 1) {
#pragma unroll
    for (int ms = 0; ms < 2; ++ms)
#pragma unroll
      for (int r = 0; r < 4; ++r) {
        int row = (w4 * 2 + ms) * 16 + lg * 4 + r;
#pragma unroll
        for (int dt = 0; dt < 4; ++dt)
          mo[row * 64 + dt * 16 + lr] = o_acc[ms][dt][r];
        if (lr == 0) ls[row] = lacc[ms][r];
      }
  }
  __syncthreads();
  if (half == 0) {
    int b = bh >> 4, hh = bh & 15;
#pragma unroll
    for (int ms = 0; ms < 2; ++ms)
#pragma unroll
      for (int r = 0; r < 4; ++r) {
        int row = (w4 * 2 + ms) * 16 + lg * 4 + r;
        float inv = 1.f / (lacc[ms][r] + ls[row]);
        int s_row = q0 + ms * 16 + lg * 4 + r;
        size_t base = ((size_t)(b * S + s_row)) * 1024 + hh * 64;
#pragma unroll
        for (int dt = 0; dt < 4; ++dt)
          out[base + dt * 16 + lr] =
              (o_acc[ms][dt][r] + mo[row * 64 + dt * 16 + lr]) * inv;
      }
  }
}

// ---------------------------------------------------------------------------
extern "C" void kernel_launch(void* const* d_in, const int* in_sizes, int n_in,
                              void* d_out, int out_size, void* d_ws, size_t ws_size,
                              hipStream_t stream) {
  const float* q  = (const float*)d_in[0];
  const float* k  = (const float*)d_in[1];
  const float* v  = (const float*)d_in[2];
  const float* wq = (const float*)d_in[3];
  const float* bq = (const float*)d_in[4];
  const float* wk = (const float*)d_in[5];
  const float* bk = (const float*)d_in[6];
  const float* wv = (const float*)d_in[7];
  const float* bv = (const float*)d_in[8];

  bf16_t* ws  = (bf16_t*)d_ws;
  constexpr size_t MW = (size_t)1 << 20;
  constexpr size_t MX = (size_t)4096 * 1024;
  bf16_t* wtq = ws;
  bf16_t* wtk = wtq + MW;
  bf16_t* wtv = wtk + MW;
  bf16_t* xq  = wtv + MW;
  bf16_t* xk  = xq + MX;
  bf16_t* xv  = xk + MX;
  bf16_t* qhd = xv + MX;
  bf16_t* khd = qhd + MX;
  bf16_t* vtd = khd + MX;
  float* out  = (float*)d_out;

  prep<<<6912, 256, 0, stream>>>(q, k, v, wq, wk, wv,
                                 xq, xk, xv, wtq, wtk, wtv);
  proj_gemm<<<768, 256, 0, stream>>>(xq, xk, xv, wtq, wtk, wtv,
                                     bq, bk, bv, qhd, khd, vtd);
  attn<<<512, 512, 0, stream>>>(qhd, khd, vtd, out);
}

// Round 13
// 186.018 us; speedup vs baseline: 1.0608x; 1.0555x over previous
//
#include <hip/hip_runtime.h>
#include <hip/hip_bf16.h>

typedef __bf16 bf16_t;
typedef bf16_t bf16x8 __attribute__((ext_vector_type(8)));
typedef bf16_t bf16x4 __attribute__((ext_vector_type(4)));
typedef short  short4v __attribute__((ext_vector_type(4)));
typedef float  f32x4  __attribute__((ext_vector_type(4)));

#define MFMA16(a,b,c) __builtin_amdgcn_mfma_f32_16x16x32_bf16(a, b, c, 0, 0, 0)

constexpr int S = 2048, H = 16, Dh = 64;
constexpr int N = H * Dh;   // 1024
constexpr int K = 1024;     // E
constexpr float QSCALE = 0.125f * 1.4426950408889634f;  // 1/sqrt(64) * log2(e)

static __device__ inline void load_lds16(const bf16_t* g, bf16_t* l) {
  __builtin_amdgcn_global_load_lds(
      (const __attribute__((address_space(1))) void*)g,
      (__attribute__((address_space(3))) void*)l, 16, 0, 0);
}

static __device__ inline ushort f2bb(float x) {
  bf16_t h = (bf16_t)x;
  return __builtin_bit_cast(ushort, h);
}

// ---------------------------------------------------------------------------
// prep (R5-verified, unchanged): blocks 0..6143 convert X fp32->bf16;
// blocks 6144..6911 transpose W.
// ---------------------------------------------------------------------------
__global__ __launch_bounds__(256) void prep(
    const float* __restrict__ q, const float* __restrict__ k,
    const float* __restrict__ v,
    const float* __restrict__ wq, const float* __restrict__ wk,
    const float* __restrict__ wv,
    bf16_t* __restrict__ xq, bf16_t* __restrict__ xk, bf16_t* __restrict__ xv,
    bf16_t* __restrict__ wtq, bf16_t* __restrict__ wtk, bf16_t* __restrict__ wtv) {
  __shared__ ushort tile[64][68];
  int bx = blockIdx.x, t = threadIdx.x;
  if (bx < 6144) {
    int z = bx >> 11, bb = bx & 2047;
    const float* xi = z == 0 ? q : z == 1 ? k : v;
    bf16_t*      xo = z == 0 ? xq : z == 1 ? xk : xv;
    size_t idx = ((size_t)bb * 256 + t) * 8;
    float4 a = *(const float4*)&xi[idx];
    float4 b = *(const float4*)&xi[idx + 4];
    bf16x8 w;
    w[0] = (bf16_t)a.x; w[1] = (bf16_t)a.y; w[2] = (bf16_t)a.z; w[3] = (bf16_t)a.w;
    w[4] = (bf16_t)b.x; w[5] = (bf16_t)b.y; w[6] = (bf16_t)b.z; w[7] = (bf16_t)b.w;
    *(bf16x8*)&xo[idx] = w;
  } else {
    int zz = bx - 6144;
    int z = zz >> 8, bb = zz & 255;
    const float* wi = z == 0 ? wq : z == 1 ? wk : wv;
    ushort*      wo = (ushort*)(z == 0 ? wtq : z == 1 ? wtk : wtv);
    int k0 = (bb >> 4) * 64, n0 = (bb & 15) * 64;
    for (int i = 0; i < 4; ++i) {
      int idx4 = (i * 256 + t) * 4;
      int r = idx4 >> 6, c = idx4 & 63;
      float4 vv = *(const float4*)&wi[(size_t)(k0 + r) * N + n0 + c];
      tile[r][c] = f2bb(vv.x); tile[r][c + 1] = f2bb(vv.y);
      tile[r][c + 2] = f2bb(vv.z); tile[r][c + 3] = f2bb(vv.w);
    }
    __syncthreads();
    for (int i = 0; i < 4; ++i) {
      int idx4 = (i * 256 + t) * 4;
      int r = idx4 >> 6, c = idx4 & 63;
      ushort4 vv;
      vv.x = tile[c][r]; vv.y = tile[c + 1][r];
      vv.z = tile[c + 2][r]; vv.w = tile[c + 3][r];
      *(ushort4*)&wo[(size_t)(n0 + r) * K + k0 + c] = vv;
    }
  }
}

// ---------------------------------------------------------------------------
// Projection GEMM (R13): DOUBLE-BUFFERED DMA STAGING, ONE barrier per K-step.
//   R12 diagnosis: the m97 2-barrier loop issues the 8 global_load_lds for
//   tile ko and immediately hits the 2nd __syncthreads() -> its mandatory
//   vmcnt(0) drain exposes full staging latency EVERY K-step.  At K=1024
//   (16 steps) this is ~60% stall (MfmaUtil 16%, FETCH already compulsory).
//   Fix (attn-v8's proven race-free shape, T3-minimum recipe): stage tile
//   ko+1 into buf^1, compute tile ko from buf, ONE barrier that both drains
//   the in-flight DMAs (a full compute phase after issue) and retires the
//   buf reads.  Hazards: buf^1 reads retired at the previous barrier; tile
//   ko+2 writes buf only after the barrier retiring tile-ko reads.
//   LDS 34.8 -> 64 KB (2 blocks/CU); XCD-chunked mapping + XOR swizzle +
//   LDS-staged epilogue unchanged.
// ---------------------------------------------------------------------------
__global__ __launch_bounds__(256) void proj_gemm(
    const bf16_t* __restrict__ xq, const bf16_t* __restrict__ xk,
    const bf16_t* __restrict__ xv,
    const bf16_t* __restrict__ wtq, const bf16_t* __restrict__ wtk,
    const bf16_t* __restrict__ wtv,
    const float* __restrict__ bq, const float* __restrict__ bk,
    const float* __restrict__ bv,
    bf16_t* __restrict__ qh, bf16_t* __restrict__ kh, bf16_t* __restrict__ vt) {
  int bid = blockIdx.x;                       // 0..767
  int logical = (bid & 7) * 96 + (bid >> 3);  // XCD-chunked, bijective
  int mode = logical >> 8;                    // 256 logicals per mode
  int rem = logical & 255;
  int gx = rem & 7;                           // N-tile (fastest within XCD)
  int gy = rem >> 3;                          // M-tile

  const bf16_t* X  = mode == 0 ? xq  : mode == 1 ? xk  : wtv;  // A rows
  const bf16_t* Wt = mode == 0 ? wtq : mode == 1 ? wtk : xv;   // B rows
  const float*  Bi = mode == 0 ? bq  : mode == 1 ? bk  : bv;

  // 64 KB: buf b at b*16384 (A 8192 elem | B 8192 elem).  Epilogue Cs
  // overlay (17408 elem) reuses the front after the final barrier.
  __shared__ __align__(16) bf16_t smem[32768];
  bf16_t* Cs = smem;

  int tid = threadIdx.x;
  int wave = tid >> 6, lane = tid & 63;
  int lr = lane & 15, lg = lane >> 4;
  int lrow = lane >> 3, lchunk = lane & 7;
  int m0 = (mode < 2 ? gy : gx) * 128;
  int n0 = (mode < 2 ? gx : gy) * 128;
  int wm = (wave >> 1) * 64, wn = (wave & 1) * 64;

  f32x4 acc[4][4];
  for (int i = 0; i < 4; ++i)
    for (int j = 0; j < 4; ++j) acc[i][j] = (f32x4){0.f, 0.f, 0.f, 0.f};

  // per-thread staging geometry (4 rows per matrix per thread)
  int srow[4], sgc[4];
  for (int j = 0; j < 4; ++j) {
    srow[j] = wave * 32 + j * 8 + lrow;
    sgc[j] = (lchunk ^ (srow[j] & 7)) * 8;
  }

  // prologue: stage tile 0 into buf0; barrier drains it
  for (int j = 0; j < 4; ++j) {
    int r = srow[j];
    load_lds16(&X [(size_t)(m0 + r) * K + sgc[j]], &smem[r * 64 + lchunk * 8]);
    load_lds16(&Wt[(size_t)(n0 + r) * K + sgc[j]], &smem[8192 + r * 64 + lchunk * 8]);
  }
  __syncthreads();

  for (int ko = 0; ko < K / 64; ++ko) {
    int cur = ko & 1;
    // issue tile ko+1 staging FIRST: DMAs fly during the compute phase and
    // are drained by the single barrier at the end of this iteration.
    if (ko + 1 < K / 64) {
      bf16_t* Ab = smem + (cur ^ 1) * 16384;
      for (int j = 0; j < 4; ++j) {
        int r = srow[j];
        load_lds16(&X [(size_t)(m0 + r) * K + (ko + 1) * 64 + sgc[j]],
                   &Ab[r * 64 + lchunk * 8]);
        load_lds16(&Wt[(size_t)(n0 + r) * K + (ko + 1) * 64 + sgc[j]],
                   &Ab[8192 + r * 64 + lchunk * 8]);
      }
    }
    const bf16_t* Abase = smem + cur * 16384;
    const bf16_t* Bbase = Abase + 8192;
    for (int kk = 0; kk < 2; ++kk) {
      bf16x8 af[4], bfr[4];
      for (int i = 0; i < 4; ++i) {
        int rr = wm + i * 16 + lr;
        af[i] = *(const bf16x8*)&Abase[rr * 64 + ((((kk << 2) | lg) ^ (rr & 7)) * 8)];
      }
      for (int j = 0; j < 4; ++j) {
        int rr = wn + j * 16 + lr;
        bfr[j] = *(const bf16x8*)&Bbase[rr * 64 + ((((kk << 2) | lg) ^ (rr & 7)) * 8)];
      }
      for (int i = 0; i < 4; ++i)
        for (int j = 0; j < 4; ++j)
          acc[i][j] = MFMA16(af[i], bfr[j], acc[i][j]);
    }
    __syncthreads();   // drains tile ko+1 DMAs; retires reads of buf[cur]
  }

  float badd[4][4][4];
  if (mode < 2) {
    float bvv[4];
    for (int j = 0; j < 4; ++j) bvv[j] = Bi[n0 + wn + j * 16 + lr];
    for (int i = 0; i < 4; ++i)
      for (int j = 0; j < 4; ++j)
        for (int r = 0; r < 4; ++r) badd[i][j][r] = bvv[j];
  } else {
    for (int i = 0; i < 4; ++i)
      for (int r = 0; r < 4; ++r) {
        float bm = Bi[m0 + wm + i * 16 + lg * 4 + r];
        for (int j = 0; j < 4; ++j) badd[i][j][r] = bm;
      }
  }

  // epilogue: Cs overlay (front of smem; all staging reads retired above)
  for (int i = 0; i < 4; ++i)
    for (int j = 0; j < 4; ++j)
      for (int r = 0; r < 4; ++r) {
        float vvv = acc[i][j][r] + badd[i][j][r];
        if (mode == 0) vvv *= QSCALE;
        Cs[(size_t)(wm + i * 16 + lg * 4 + r) * 136 + wn + j * 16 + lr] = (bf16_t)vvv;
      }
  __syncthreads();

  bf16_t* o = mode == 0 ? qh : mode == 1 ? kh : vt;
  for (int p = 0; p < 8; ++p) {
    int idx = p * 256 + tid;
    int row = idx >> 4, ch = idx & 15;
    bf16x8 vv = *(const bf16x8*)&Cs[(size_t)row * 136 + ch * 8];
    size_t dst;
    if (mode < 2) {
      int m_g = m0 + row, n_g = n0 + ch * 8;
      int b = m_g >> 11, s = m_g & 2047;
      int h = n_g >> 6, d = n_g & 63;
      dst = (((size_t)(b * 16 + h) * 2048) + s) * 64 + d;
    } else {
      int w_g = m0 + row, t_g = n0 + ch * 8;
      int b = t_g >> 11, s = t_g & 2047;
      dst = ((size_t)(b * 1024 + w_g)) * 2048 + s;
    }
    *(uint4*)&o[dst] = __builtin_bit_cast(uint4, vv);
  }
}

// ---------------------------------------------------------------------------
// Flash attention v11 (R10-verified session best, unchanged): v7 loop
// structure (single 33 KB buffer, 2 barriers/iter, KV-split halves, paired
// K=32 PV, register-prefetch staging) + XCD-chunked flat block mapping.
// Note: attn's 2-barrier loop does NOT have proj's exposed-latency problem
// -- its staging is register-prefetched one full iteration early.
// ---------------------------------------------------------------------------
__global__ __launch_bounds__(512, 2) void attn(
    const bf16_t* __restrict__ qh, const bf16_t* __restrict__ kh,
    const bf16_t* __restrict__ vt, float* __restrict__ out) {
  // staging: [half][kt 8KB | vs 8KB] = 32 KB; merge overlay needs 33280 B
  __shared__ __align__(16) bf16_t smem[16640];

  int tid = threadIdx.x, wave = tid >> 6, lane = tid & 63;
  int lr = lane & 15, lg = lane >> 4;
  int half = wave >> 2, w4 = wave & 3;

  int bid = blockIdx.x;
  int logical = (bid & 7) * 64 + (bid >> 3);  // XCD-chunked, bijective (512%8==0)
  int bh = logical >> 4;
  int q0 = (logical & 15) * 128 + w4 * 32;

  bf16_t* kt = smem + half * 8192;
  bf16_t* vs = kt + 4096;

  const bf16_t* qg = qh + (size_t)bh * S * Dh;
  const bf16_t* kg = kh + (size_t)bh * S * Dh;
  const bf16_t* vg = vt + (size_t)bh * Dh * S;

  bf16x8 bqf[2][2];
#pragma unroll
  for (int ms = 0; ms < 2; ++ms)
#pragma unroll
    for (int kk = 0; kk < 2; ++kk)
      bqf[ms][kk] = *(const bf16x8*)
          &qg[(size_t)(q0 + ms * 16 + lr) * 64 + kk * 32 + lg * 8];

  bf16x8 ones8;
#pragma unroll
  for (int j = 0; j < 8; ++j) ones8[j] = (bf16_t)1.0f;

  f32x4 o_acc[2][4], lacc[2];
#pragma unroll
  for (int ms = 0; ms < 2; ++ms) {
    lacc[ms] = (f32x4){0.f, 0.f, 0.f, 0.f};
#pragma unroll
    for (int dt = 0; dt < 4; ++dt) o_acc[ms][dt] = (f32x4){0.f, 0.f, 0.f, 0.f};
  }

  // staging geometry within the half (256 threads cover 64 rows x 8 chunks,
  // two 16B slots per thread per matrix)
  int lrow = lane >> 3, lchunk = lane & 7;
  int srow0 = w4 * 16 + lrow;
  int srow1 = srow0 + 8;
  int sgc = (lchunk ^ (srow0 & 7)) * 8;   // (srow1&7)==(srow0&7)
  int ld0 = srow0 * 64 + lchunk * 8;
  int ld1 = ld0 + 512;                    // +8 rows

  int cb = half * (S / 2);                // this half's kv col base

  // prologue: prefetch this half's tile 0 into VGPRs
  uint4 kr0 = *(const uint4*)&kg[(size_t)(cb + srow0) * 64 + sgc];
  uint4 kr1 = *(const uint4*)&kg[(size_t)(cb + srow1) * 64 + sgc];
  uint4 vr0 = *(const uint4*)&vg[(size_t)srow0 * S + cb + sgc];
  uint4 vr1 = *(const uint4*)&vg[(size_t)srow1 * S + cb + sgc];

  int sw = lr & 7, p4 = (lg & 1) * 4;

  constexpr int NITH = (S / 2) / 64;      // 16
  for (int it = 0; it < NITH; ++it) {
    __syncthreads();                      // prev iter's LDS reads retired
    *(uint4*)&kt[ld0] = kr0;              // waits vmcnt for OWN loads only
    *(uint4*)&kt[ld1] = kr1;
    *(uint4*)&vs[ld0] = vr0;
    *(uint4*)&vs[ld1] = vr1;
    if (it + 1 < NITH) {                  // prefetch tile i+1; lands in compute
      int sk1 = cb + (it + 1) * 64;
      kr0 = *(const uint4*)&kg[(size_t)(sk1 + srow0) * 64 + sgc];
      kr1 = *(const uint4*)&kg[(size_t)(sk1 + srow1) * 64 + sgc];
      vr0 = *(const uint4*)&vg[(size_t)srow0 * S + sk1 + sgc];
      vr1 = *(const uint4*)&vg[(size_t)srow1 * S + sk1 + sgc];
    }
    __syncthreads();                      // ds_writes visible to half's waves

    // QK^T (swapped operands: A=K, B=Q -> lane holds scores for q-row lr),
    // processed in two tp groups of 32 k-cols; st/ak transient per group.
    // pa8[ms][tp] slot j holds P[q=lr][k = tp*32 + (j>>2)*16 + lg*4 + (j&3)]
    bf16x8 pa8[2][2];
#pragma unroll
    for (int tp = 0; tp < 2; ++tp) {
      f32x4 st[2][2];
#pragma unroll
      for (int ms = 0; ms < 2; ++ms)
#pragma unroll
        for (int ts = 0; ts < 2; ++ts) st[ms][ts] = (f32x4){0.f, 0.f, 0.f, 0.f};
#pragma unroll
      for (int ts = 0; ts < 2; ++ts) {
        int t = tp * 2 + ts;
        const bf16_t* krow = &kt[(t * 16 + lr) * 64];
        bf16x8 ak0 = *(const bf16x8*)&krow[(lg ^ sw) * 8];
        bf16x8 ak1 = *(const bf16x8*)&krow[((4 + lg) ^ sw) * 8];
#pragma unroll
        for (int ms = 0; ms < 2; ++ms) {
          st[ms][ts] = MFMA16(ak0, bqf[ms][0], st[ms][ts]);
          st[ms][ts] = MFMA16(ak1, bqf[ms][1], st[ms][ts]);
        }
      }
#pragma unroll
      for (int ms = 0; ms < 2; ++ms)
#pragma unroll
        for (int r = 0; r < 4; ++r) {
          pa8[ms][tp][r]     = (bf16_t)__builtin_amdgcn_exp2f(st[ms][0][r]);
          pa8[ms][tp][r + 4] = (bf16_t)__builtin_amdgcn_exp2f(st[ms][1][r]);
        }
    }

    // PV at full k=32 rate; V fragments built transiently per dt, shared by
    // both Q-tiles.
#pragma unroll
    for (int tp = 0; tp < 2; ++tp) {
      int g0 = tp * 4 + (lg >> 1);
#pragma unroll
      for (int dt = 0; dt < 4; ++dt) {
        const bf16_t* vrow = &vs[(dt * 16 + lr) * 64];
        bf16x4 lo = *(const bf16x4*)&vrow[((g0      ^ sw) * 8) + p4];
        bf16x4 hi = *(const bf16x4*)&vrow[(((g0 + 2) ^ sw) * 8) + p4];
        bf16x8 bb;
#pragma unroll
        for (int j = 0; j < 4; ++j) { bb[j] = lo[j]; bb[j + 4] = hi[j]; }
#pragma unroll
        for (int ms = 0; ms < 2; ++ms)
          o_acc[ms][dt] = MFMA16(pa8[ms][tp], bb, o_acc[ms][dt]);
      }
#pragma unroll
      for (int ms = 0; ms < 2; ++ms)
        lacc[ms] = MFMA16(pa8[ms][tp], ones8, lacc[ms]);
    }
  }

  // ---- merge halves via LDS overlay (reuses staging space) ----
  __syncthreads();                        // all staging reads/writes retired
  float* mo = (float*)smem;               // [8 q-subtiles][16 rows][64 cols]
  float* ls = mo + 8 * 16 * 64;           // [8][16] rowsums

  if (half == 1) {
#pragma unroll
    for (int ms = 0; ms < 2; ++ms)
#pragma unroll
      for (int r = 0; r < 4; ++r) {
        int row = (w4 * 2 + ms) * 16 + lg * 4 + r;
#pragma unroll
        for (int dt = 0; dt < 4; ++dt)
          mo[row * 64 + dt * 16 + lr] = o_acc[ms][dt][r];
        if (lr == 0) ls[row] = lacc[ms][r];
      }
  }
  __syncthreads();
  if (half == 0) {
    int b = bh >> 4, hh = bh & 15;
#pragma unroll
    for (int ms = 0; ms < 2; ++ms)
#pragma unroll
      for (int r = 0; r < 4; ++r) {
        int row = (w4 * 2 + ms) * 16 + lg * 4 + r;
        float inv = 1.f / (lacc[ms][r] + ls[row]);
        int s_row = q0 + ms * 16 + lg * 4 + r;
        size_t base = ((size_t)(b * S + s_row)) * 1024 + hh * 64;
#pragma unroll
        for (int dt = 0; dt < 4; ++dt)
          out[base + dt * 16 + lr] =
              (o_acc[ms][dt][r] + mo[row * 64 + dt * 16 + lr]) * inv;
      }
  }
}

// ---------------------------------------------------------------------------
extern "C" void kernel_launch(void* const* d_in, const int* in_sizes, int n_in,
                              void* d_out, int out_size, void* d_ws, size_t ws_size,
                              hipStream_t stream) {
  const float* q  = (const float*)d_in[0];
  const float* k  = (const float*)d_in[1];
  const float* v  = (const float*)d_in[2];
  const float* wq = (const float*)d_in[3];
  const float* bq = (const float*)d_in[4];
  const float* wk = (const float*)d_in[5];
  const float* bk = (const float*)d_in[6];
  const float* wv = (const float*)d_in[7];
  const float* bv = (const float*)d_in[8];

  bf16_t* ws  = (bf16_t*)d_ws;
  constexpr size_t MW = (size_t)1 << 20;
  constexpr size_t MX = (size_t)4096 * 1024;
  bf16_t* wtq = ws;
  bf16_t* wtk = wtq + MW;
  bf16_t* wtv = wtk + MW;
  bf16_t* xq  = wtv + MW;
  bf16_t* xk  = xq + MX;
  bf16_t* xv  = xk + MX;
  bf16_t* qhd = xv + MX;
  bf16_t* khd = qhd + MX;
  bf16_t* vtd = khd + MX;
  float* out  = (float*)d_out;

  prep<<<6912, 256, 0, stream>>>(q, k, v, wq, wk, wv,
                                 xq, xk, xv, wtq, wtk, wtv);
  proj_gemm<<<768, 256, 0, stream>>>(xq, xk, xv, wtq, wtk, wtv,
                                     bq, bk, bv, qhd, khd, vtd);
  attn<<<512, 512, 0, stream>>>(qhd, khd, vtd, out);
}